// Round 5
// baseline (951.245 us; speedup 1.0000x reference)
//
#include <hip/hip_runtime.h>

#define N_NODES 10000
#define N_EDGES 160000
#define DVAL    512
#define DEPTH   10
#define MPAD    10048   // N_NODES padded to 64 for GEMM A-tiles

typedef __attribute__((ext_vector_type(8))) short short8;
typedef __attribute__((ext_vector_type(4))) float f32x4;
typedef __attribute__((ext_vector_type(4))) unsigned short u16x4;
typedef __attribute__((ext_vector_type(8))) unsigned short u16x8;

static __device__ inline unsigned short f2bf(float f) {
    unsigned u = __float_as_uint(f);
    unsigned r = (u + 0x7FFF + ((u >> 16) & 1)) >> 16;  // round-to-nearest-even
    return (unsigned short)r;
}
static __device__ inline float bf2f(unsigned short h) {
    return __uint_as_float(((unsigned)h) << 16);
}

// ---------------- CSR build ----------------

__global__ void zero_int_kernel(int* p, int n) {
    int i = blockIdx.x * 256 + threadIdx.x;
    if (i < n) p[i] = 0;
}

__global__ void count_deg_kernel(const int* __restrict__ dst, int* __restrict__ deg, int n) {
    int i = blockIdx.x * 256 + threadIdx.x;
    if (i < n) atomicAdd(&deg[dst[i]], 1);
}

__global__ __launch_bounds__(1024) void scan_kernel(const int* __restrict__ deg,
                                                    int* __restrict__ row_ptr,
                                                    int* __restrict__ cursor) {
    __shared__ int sums[1024];
    const int tid = threadIdx.x;
    const int CH = 10;
    int base = tid * CH;
    int local[CH];
    int s = 0;
#pragma unroll
    for (int i = 0; i < CH; i++) {
        int idx = base + i;
        int v = (idx < N_NODES) ? deg[idx] : 0;
        local[i] = s;
        s += v;
    }
    sums[tid] = s;
    __syncthreads();
    for (int off = 1; off < 1024; off <<= 1) {
        int v = (tid >= off) ? sums[tid - off] : 0;
        __syncthreads();
        sums[tid] += v;
        __syncthreads();
    }
    int chunk_base = (tid > 0) ? sums[tid - 1] : 0;
#pragma unroll
    for (int i = 0; i < CH; i++) {
        int idx = base + i;
        if (idx < N_NODES) {
            int v = chunk_base + local[i];
            row_ptr[idx] = v;
            cursor[idx] = v;
        }
    }
    if (tid == 1023) row_ptr[N_NODES] = sums[1023];
}

__global__ void fill_edges_kernel(const int* __restrict__ src, const int* __restrict__ dst,
                                  int* __restrict__ cursor, int* __restrict__ esrc, int n) {
    int i = blockIdx.x * 256 + threadIdx.x;
    if (i < n) {
        int p = atomicAdd(&cursor[dst[i]], 1);
        esrc[p] = src[i];
    }
}

// ---------------- W prep: transpose + split to bf16 hi/lo ----------------
// Ws[l][k][n] fp32  ->  Wt_hi/Wt_lo[l][n][k] bf16
__global__ __launch_bounds__(256) void transpose_split_kernel(const float* __restrict__ Ws,
                                                              unsigned short* __restrict__ Wt_hi,
                                                              unsigned short* __restrict__ Wt_lo) {
    __shared__ float tile[64][65];
    const int l = blockIdx.z;
    const int kb = blockIdx.x * 64;
    const int nb = blockIdx.y * 64;
    const int t = threadIdx.x;
    const size_t base = (size_t)l * 512 * 512;
#pragma unroll
    for (int i = 0; i < 4; i++) {
        int k = (t >> 4) + i * 16;
        int n4 = (t & 15) * 4;
        float4 v = *(const float4*)(Ws + base + (size_t)(kb + k) * 512 + nb + n4);
        tile[k][n4 + 0] = v.x;
        tile[k][n4 + 1] = v.y;
        tile[k][n4 + 2] = v.z;
        tile[k][n4 + 3] = v.w;
    }
    __syncthreads();
#pragma unroll
    for (int i = 0; i < 4; i++) {
        int n = (t >> 4) + i * 16;
        int k4 = (t & 15) * 4;
        u16x4 h, lo;
#pragma unroll
        for (int j = 0; j < 4; j++) {
            float v = tile[k4 + j][n];
            unsigned short hb = f2bf(v);
            h[j] = hb;
            lo[j] = f2bf(v - bf2f(hb));
        }
        size_t o = base + (size_t)(nb + n) * 512 + kb + k4;
        *(u16x4*)(Wt_hi + o) = h;
        *(u16x4*)(Wt_lo + o) = lo;
    }
}

// ---------------- layer kernels ----------------

__global__ __launch_bounds__(64) void aggregate6_kernel(const float* __restrict__ feat,
                                                        const int* __restrict__ row_ptr,
                                                        const int* __restrict__ esrc,
                                                        float* __restrict__ agg6) {
    int node = blockIdx.x;
    int l = threadIdx.x;
    if (l >= 6) return;
    int start = row_ptr[node], end = row_ptr[node + 1];
    float acc = 0.f;
    for (int e = start; e < end; e++) acc += feat[esrc[e] * 6 + l];
    agg6[node * 6 + l] = acc;
}

__global__ __launch_bounds__(256) void input_layer_kernel(const float* __restrict__ agg6,
                                                          const float* __restrict__ W_in,
                                                          const float* __restrict__ b_in,
                                                          float* __restrict__ x) {
    int node = blockIdx.x;
    int j = threadIdx.x;
    float a[6];
#pragma unroll
    for (int k = 0; k < 6; k++) a[k] = agg6[node * 6 + k];
#pragma unroll
    for (int r = 0; r < 2; r++) {
        int jj = j + r * 256;
        float s = b_in[jj];
#pragma unroll
        for (int k = 0; k < 6; k++) s += a[k] * W_in[k * 512 + jj];
        x[(size_t)node * 512 + jj] = fmaxf(s, 0.f);
    }
}

// XCD-pinned chunked aggregation, two edge-streams per wave (nodes g, g+1),
// bf16 hi/lo split epilogue. chunk = blockIdx & 7 pins each 64-col slice of x
// (2.56 MB) to one XCD's L2 under round-robin block->XCD dispatch.
__global__ __launch_bounds__(256) void aggregate_split_kernel(const float* __restrict__ x,
                                                              const int* __restrict__ row_ptr,
                                                              const int* __restrict__ esrc,
                                                              unsigned short* __restrict__ agg_hi,
                                                              unsigned short* __restrict__ agg_lo) {
    const int b = blockIdx.x;
    const int chunk = b & 7;
    const int w = threadIdx.x >> 6;
    const int lane = threadIdx.x & 63;
    const int g = (b >> 3) * 8 + w * 2;  // this wave handles nodes g and g+1
    const int col = chunk * 64 + lane;
    const int s0 = row_ptr[g];
    const int m0 = row_ptr[g + 1];
    const int m1 = row_ptr[g + 2];

    float p0 = 0.f, p1 = 0.f, p2 = 0.f, p3 = 0.f;
    float q0 = 0.f, q1 = 0.f, q2 = 0.f, q3 = 0.f;
    int e0 = s0, e1 = m0;
    // interleaved main loop: 8 independent loads in flight per lane
    while (e0 + 4 <= m0 && e1 + 4 <= m1) {
        int a0 = esrc[e0], a1 = esrc[e0 + 1], a2 = esrc[e0 + 2], a3 = esrc[e0 + 3];
        int b0 = esrc[e1], b1 = esrc[e1 + 1], b2 = esrc[e1 + 2], b3 = esrc[e1 + 3];
        p0 += x[(size_t)a0 * 512 + col];
        p1 += x[(size_t)a1 * 512 + col];
        p2 += x[(size_t)a2 * 512 + col];
        p3 += x[(size_t)a3 * 512 + col];
        q0 += x[(size_t)b0 * 512 + col];
        q1 += x[(size_t)b1 * 512 + col];
        q2 += x[(size_t)b2 * 512 + col];
        q3 += x[(size_t)b3 * 512 + col];
        e0 += 4; e1 += 4;
    }
    for (; e0 + 4 <= m0; e0 += 4) {
        int a0 = esrc[e0], a1 = esrc[e0 + 1], a2 = esrc[e0 + 2], a3 = esrc[e0 + 3];
        p0 += x[(size_t)a0 * 512 + col];
        p1 += x[(size_t)a1 * 512 + col];
        p2 += x[(size_t)a2 * 512 + col];
        p3 += x[(size_t)a3 * 512 + col];
    }
    for (; e0 < m0; e0++) p0 += x[(size_t)esrc[e0] * 512 + col];
    for (; e1 + 4 <= m1; e1 += 4) {
        int b0 = esrc[e1], b1 = esrc[e1 + 1], b2 = esrc[e1 + 2], b3 = esrc[e1 + 3];
        q0 += x[(size_t)b0 * 512 + col];
        q1 += x[(size_t)b1 * 512 + col];
        q2 += x[(size_t)b2 * 512 + col];
        q3 += x[(size_t)b3 * 512 + col];
    }
    for (; e1 < m1; e1++) q0 += x[(size_t)esrc[e1] * 512 + col];

    float sp = (p0 + p1) + (p2 + p3);
    float sq = (q0 + q1) + (q2 + q3);
    unsigned short hp = f2bf(sp);
    unsigned short hq = f2bf(sq);
    size_t op = (size_t)g * 512 + col;
    agg_hi[op] = hp;
    agg_lo[op] = f2bf(sp - bf2f(hp));
    agg_hi[op + 512] = hq;
    agg_lo[op + 512] = f2bf(sq - bf2f(hq));
}

// ---------------- no-LDS register-fragment MFMA GEMM ----------------
// C[M,512] = A @ W + bias, split-bf16 (hh + hl + lh).
// One wave per 64x64 tile; fragments loaded straight from global (L2-hit);
// manual double-buffer prefetch; no LDS, no barriers.
// Block swizzle: xcd = blockIdx&7 = m&7, so the 8 n-blocks sharing an A-slice
// run on one XCD (A fetched once per XCD; W hi+lo = 2 MB stays L2-resident).
struct Frags {
    short8 ah[4], al[4], bh[4], bl[4];
};

static __device__ inline void load_frags(Frags& f,
                                         const unsigned short* pAh, const unsigned short* pAl,
                                         const unsigned short* pBh, const unsigned short* pBl,
                                         int kb) {
#pragma unroll
    for (int t = 0; t < 4; t++) {
        f.ah[t] = *(const short8*)(pAh + (size_t)t * 16 * 512 + kb);
        f.al[t] = *(const short8*)(pAl + (size_t)t * 16 * 512 + kb);
        f.bh[t] = *(const short8*)(pBh + (size_t)t * 16 * 512 + kb);
        f.bl[t] = *(const short8*)(pBl + (size_t)t * 16 * 512 + kb);
    }
}

static __device__ inline void do_mfma(const Frags& f, f32x4 acc[4][4]) {
#pragma unroll
    for (int mt = 0; mt < 4; mt++)
#pragma unroll
        for (int nt = 0; nt < 4; nt++)
            acc[mt][nt] = __builtin_amdgcn_mfma_f32_16x16x32_bf16(f.ah[mt], f.bh[nt], acc[mt][nt], 0, 0, 0);
#pragma unroll
    for (int mt = 0; mt < 4; mt++)
#pragma unroll
        for (int nt = 0; nt < 4; nt++) {
            acc[mt][nt] = __builtin_amdgcn_mfma_f32_16x16x32_bf16(f.ah[mt], f.bl[nt], acc[mt][nt], 0, 0, 0);
            acc[mt][nt] = __builtin_amdgcn_mfma_f32_16x16x32_bf16(f.al[mt], f.bh[nt], acc[mt][nt], 0, 0, 0);
        }
}

__global__ __launch_bounds__(64) void gemm_mfma_kernel(const unsigned short* __restrict__ Ah,
                                                       const unsigned short* __restrict__ Al,
                                                       const unsigned short* __restrict__ Bh,
                                                       const unsigned short* __restrict__ Bl,
                                                       const float* __restrict__ bias,
                                                       float* __restrict__ C, int M) {
    const int b = blockIdx.x;
    const int mblk = (b & 7) + ((b >> 6) << 3);
    const int nblk = (b >> 3) & 7;
    const int mblocks = (M + 63) >> 6;
    if (mblk >= mblocks) return;

    const int lane = threadIdx.x;
    const int l15 = lane & 15;
    const int quad = lane >> 4;
    const int qk = quad * 8;

    const unsigned short* pAh = Ah + (size_t)(mblk * 64 + l15) * 512 + qk;
    const unsigned short* pAl = Al + (size_t)(mblk * 64 + l15) * 512 + qk;
    const unsigned short* pBh = Bh + (size_t)(nblk * 64 + l15) * 512 + qk;
    const unsigned short* pBl = Bl + (size_t)(nblk * 64 + l15) * 512 + qk;

    f32x4 acc[4][4];
#pragma unroll
    for (int i = 0; i < 4; i++)
#pragma unroll
        for (int j = 0; j < 4; j++) acc[i][j] = (f32x4)0.f;

    Frags f0, f1;
    load_frags(f0, pAh, pAl, pBh, pBl, 0);
#pragma unroll
    for (int kb = 0; kb < 512; kb += 64) {
        load_frags(f1, pAh, pAl, pBh, pBl, kb + 32);
        do_mfma(f0, acc);
        if (kb + 64 < 512) load_frags(f0, pAh, pAl, pBh, pBl, kb + 64);
        do_mfma(f1, acc);
    }

    // epilogue: bias + store (C/D: col=lane&15, row=quad*4+reg)
#pragma unroll
    for (int nt = 0; nt < 4; nt++) {
        int col = nblk * 64 + nt * 16 + l15;
        float bv = bias[col];
#pragma unroll
        for (int mt = 0; mt < 4; mt++) {
#pragma unroll
            for (int r = 0; r < 4; r++) {
                int row = mblk * 64 + mt * 16 + quad * 4 + r;
                if (row < M) C[(size_t)row * 512 + col] = acc[mt][nt][r] + bv;
            }
        }
    }
}

__global__ __launch_bounds__(256) void output_layer_kernel(const float* __restrict__ x,
                                                           const float* __restrict__ W_out,
                                                           const float* __restrict__ b_out,
                                                           float* __restrict__ out) {
    int wave = threadIdx.x >> 6;
    int lane = threadIdx.x & 63;
    int node = blockIdx.x * 4 + wave;
    if (node >= N_NODES) return;
    float s = 0.f;
#pragma unroll
    for (int r = 0; r < 8; r++) {
        int k = lane + r * 64;
        s += x[(size_t)node * 512 + k] * W_out[k];
    }
#pragma unroll
    for (int off = 32; off > 0; off >>= 1) s += __shfl_down(s, off, 64);
    if (lane == 0) out[node] = s + b_out[0];
}

// ---------------- launch ----------------

extern "C" void kernel_launch(void* const* d_in, const int* in_sizes, int n_in,
                              void* d_out, int out_size, void* d_ws, size_t ws_size,
                              hipStream_t stream) {
    const float* features = (const float*)d_in[0];
    const float* W_in     = (const float*)d_in[1];
    const float* b_in     = (const float*)d_in[2];
    const float* Ws       = (const float*)d_in[3];
    const float* bs       = (const float*)d_in[4];
    const float* W_out    = (const float*)d_in[5];
    const float* b_out    = (const float*)d_in[6];
    const int*   src      = (const int*)d_in[7];
    const int*   dst      = (const int*)d_in[8];
    float* out = (float*)d_out;

    char* p = (char*)d_ws;
    auto alloc = [&](size_t bytes) {
        char* r = p;
        p += (bytes + 255) & ~size_t(255);
        return r;
    };
    float* x    = (float*)alloc((size_t)N_NODES * DVAL * 4);
    unsigned short* agg_hi = (unsigned short*)alloc((size_t)MPAD * DVAL * 2);
    unsigned short* agg_lo = (unsigned short*)alloc((size_t)MPAD * DVAL * 2);
    float* agg6 = (float*)alloc((size_t)N_NODES * 6 * 4);
    int* deg     = (int*)alloc((size_t)N_NODES * 4);
    int* row_ptr = (int*)alloc((size_t)(N_NODES + 1) * 4);
    int* cursor  = (int*)alloc((size_t)N_NODES * 4);
    int* esrc    = (int*)alloc((size_t)N_EDGES * 4);
    unsigned short* Wt_hi = (unsigned short*)alloc((size_t)DEPTH * 512 * 512 * 2);
    unsigned short* Wt_lo = (unsigned short*)alloc((size_t)DEPTH * 512 * 512 * 2);

    // CSR build
    zero_int_kernel<<<(N_NODES + 255) / 256, 256, 0, stream>>>(deg, N_NODES);
    count_deg_kernel<<<(N_EDGES + 255) / 256, 256, 0, stream>>>(dst, deg, N_EDGES);
    scan_kernel<<<1, 1024, 0, stream>>>(deg, row_ptr, cursor);
    fill_edges_kernel<<<(N_EDGES + 255) / 256, 256, 0, stream>>>(src, dst, cursor, esrc, N_EDGES);

    // W prep (once per call)
    transpose_split_kernel<<<dim3(8, 8, DEPTH), 256, 0, stream>>>(Ws, Wt_hi, Wt_lo);

    // input layer
    aggregate6_kernel<<<N_NODES, 64, 0, stream>>>(features, row_ptr, esrc, agg6);
    input_layer_kernel<<<N_NODES, 256, 0, stream>>>(agg6, W_in, b_in, x);

    // hidden layers
    const int agg_blocks = (N_NODES / 8) * 8;       // 1250 node-groups x 8 chunks
    const int gemm_blocks = 1280;                   // swizzled (m&7)|(n<<3)|((m>>3)<<6), guarded
    for (int l = 0; l < DEPTH; l++) {
        aggregate_split_kernel<<<agg_blocks, 256, 0, stream>>>(x, row_ptr, esrc, agg_hi, agg_lo);
        gemm_mfma_kernel<<<gemm_blocks, 64, 0, stream>>>(agg_hi, agg_lo,
                                                         Wt_hi + (size_t)l * 512 * 512,
                                                         Wt_lo + (size_t)l * 512 * 512,
                                                         bs + (size_t)l * 512, x, N_NODES);
    }

    // output layer
    output_layer_kernel<<<(N_NODES + 3) / 4, 256, 0, stream>>>(x, W_out, b_out, out);
}

// Round 6
// 195.566 us; speedup vs baseline: 4.8641x; 4.8641x over previous
//
#include <hip/hip_runtime.h>

#define N_NODES 10000
#define N_EDGES 160000
#define DVAL    512
#define DEPTH   10

// ============================================================================
// Algebraic collapse: layers 2..11 + output head are LINEAR (ReLU only after
// the input layer), and segment_sum (row op) commutes with W (col op):
//   out = A^10 x1 (W1..W10 Wout) + sum_k gamma_k A^(10-k) 1 + b_out
// with w~ = W1..W10 Wout (512-vec), gamma_k = b_k . (W_{k+1}..W10 Wout) (scalar).
// Work: 10 matvecs (backward chain) + one fused input pass -> z = x1.w~ [N]
// + 10 single-column Horner aggregations r <- A r + gamma_l. All fp32.
// ============================================================================

// ---------------- CSR build ----------------

__global__ void zero_int_kernel(int* p, int n) {
    int i = blockIdx.x * 256 + threadIdx.x;
    if (i < n) p[i] = 0;
}

__global__ void count_deg_kernel(const int* __restrict__ dst, int* __restrict__ deg, int n) {
    int i = blockIdx.x * 256 + threadIdx.x;
    if (i < n) atomicAdd(&deg[dst[i]], 1);
}

__global__ __launch_bounds__(1024) void scan_kernel(const int* __restrict__ deg,
                                                    int* __restrict__ row_ptr,
                                                    int* __restrict__ cursor) {
    __shared__ int sums[1024];
    const int tid = threadIdx.x;
    const int CH = 10;
    int base = tid * CH;
    int local[CH];
    int s = 0;
#pragma unroll
    for (int i = 0; i < CH; i++) {
        int idx = base + i;
        int v = (idx < N_NODES) ? deg[idx] : 0;
        local[i] = s;
        s += v;
    }
    sums[tid] = s;
    __syncthreads();
    for (int off = 1; off < 1024; off <<= 1) {
        int v = (tid >= off) ? sums[tid - off] : 0;
        __syncthreads();
        sums[tid] += v;
        __syncthreads();
    }
    int chunk_base = (tid > 0) ? sums[tid - 1] : 0;
#pragma unroll
    for (int i = 0; i < CH; i++) {
        int idx = base + i;
        if (idx < N_NODES) {
            int v = chunk_base + local[i];
            row_ptr[idx] = v;
            cursor[idx] = v;
        }
    }
    if (tid == 1023) row_ptr[N_NODES] = sums[1023];
}

__global__ void fill_edges_kernel(const int* __restrict__ src, const int* __restrict__ dst,
                                  int* __restrict__ cursor, int* __restrict__ esrc, int n) {
    int i = blockIdx.x * 256 + threadIdx.x;
    if (i < n) {
        int p = atomicAdd(&cursor[dst[i]], 1);
        esrc[p] = src[i];
    }
}

// ---------------- weight-chain matvec: v_out = W @ v_in ; gamma = b . v_in ----
// 128 blocks x 256 threads = 512 waves, one 512-dot per wave.
__global__ __launch_bounds__(256) void matvec_gamma_kernel(const float* __restrict__ W,
                                                           const float* __restrict__ b,
                                                           const float* __restrict__ v_in,
                                                           float* __restrict__ v_out,
                                                           float* __restrict__ gamma_slot) {
    const int gw = (blockIdx.x * 256 + threadIdx.x) >> 6;  // 0..511
    const int lane = threadIdx.x & 63;
    {
        const float* row = W + (size_t)gw * 512;
        float s = 0.f;
#pragma unroll
        for (int c = 0; c < 8; c++) s += row[lane + c * 64] * v_in[lane + c * 64];
#pragma unroll
        for (int off = 32; off > 0; off >>= 1) s += __shfl_down(s, off, 64);
        if (lane == 0) v_out[gw] = s;
    }
    if (gw == 511) {
        float s = 0.f;
#pragma unroll
        for (int c = 0; c < 8; c++) s += b[lane + c * 64] * v_in[lane + c * 64];
#pragma unroll
        for (int off = 32; off > 0; off >>= 1) s += __shfl_down(s, off, 64);
        if (lane == 0) *gamma_slot = s;
    }
}

// ---------------- input aggregation: F_IN = 6 floats per node ----------------
// 8 lanes per node (6 active), 32 nodes per 256-thread block.
__global__ __launch_bounds__(256) void aggregate6_kernel(const float* __restrict__ feat,
                                                         const int* __restrict__ row_ptr,
                                                         const int* __restrict__ esrc,
                                                         float* __restrict__ agg6) {
    int t = blockIdx.x * 256 + threadIdx.x;
    int node = t >> 3;
    int c = t & 7;
    if (node >= N_NODES || c >= 6) return;
    int start = row_ptr[node], end = row_ptr[node + 1];
    float a0 = 0.f, a1 = 0.f;
    int e = start;
    for (; e + 2 <= end; e += 2) {
        a0 += feat[esrc[e] * 6 + c];
        a1 += feat[esrc[e + 1] * 6 + c];
    }
    if (e < end) a0 += feat[esrc[e] * 6 + c];
    agg6[node * 6 + c] = a0 + a1;
}

// ---------------- fused input layer + projection onto w~ ----------------
// z[node] = sum_j relu( (agg6 . W_in)_j + b_in_j ) * w~_j
__global__ __launch_bounds__(256) void input_z_kernel(const float* __restrict__ agg6,
                                                      const float* __restrict__ W_in,
                                                      const float* __restrict__ b_in,
                                                      const float* __restrict__ vtilde,
                                                      float* __restrict__ z) {
    __shared__ float red[4];
    const int node = blockIdx.x;
    const int j = threadIdx.x;
    const int lane = j & 63;
    const int wave = j >> 6;
    float a[6];
#pragma unroll
    for (int k = 0; k < 6; k++) a[k] = agg6[node * 6 + k];
    float s = 0.f;
#pragma unroll
    for (int r = 0; r < 2; r++) {
        int jj = j + r * 256;
        float t = b_in[jj];
#pragma unroll
        for (int k = 0; k < 6; k++) t += a[k] * W_in[k * 512 + jj];
        s += fmaxf(t, 0.f) * vtilde[jj];
    }
#pragma unroll
    for (int off = 32; off > 0; off >>= 1) s += __shfl_down(s, off, 64);
    if (lane == 0) red[wave] = s;
    __syncthreads();
    if (j == 0) z[node] = (red[0] + red[1]) + (red[2] + red[3]);
}

// ---------------- Horner step: r_out = A r_in + gamma[gi] (+ b_out at end) ----
__global__ __launch_bounds__(256) void col_agg_kernel(const float* __restrict__ r_in,
                                                      const int* __restrict__ row_ptr,
                                                      const int* __restrict__ esrc,
                                                      const float* __restrict__ gamma,
                                                      int gi,
                                                      const float* __restrict__ b_out,
                                                      int is_last,
                                                      float* __restrict__ r_out) {
    int i = blockIdx.x * 256 + threadIdx.x;
    if (i >= N_NODES) return;
    int s = row_ptr[i], e = row_ptr[i + 1];
    float a0 = 0.f, a1 = 0.f, a2 = 0.f, a3 = 0.f;
    int p = s;
    for (; p + 4 <= e; p += 4) {
        int i0 = esrc[p], i1 = esrc[p + 1], i2 = esrc[p + 2], i3 = esrc[p + 3];
        a0 += r_in[i0];
        a1 += r_in[i1];
        a2 += r_in[i2];
        a3 += r_in[i3];
    }
    for (; p < e; p++) a0 += r_in[esrc[p]];
    float res = (a0 + a1) + (a2 + a3) + gamma[gi];
    if (is_last) res += b_out[0];
    r_out[i] = res;
}

// ---------------- launch ----------------

extern "C" void kernel_launch(void* const* d_in, const int* in_sizes, int n_in,
                              void* d_out, int out_size, void* d_ws, size_t ws_size,
                              hipStream_t stream) {
    const float* features = (const float*)d_in[0];  // [10000, 6]
    const float* W_in     = (const float*)d_in[1];  // [6, 512]
    const float* b_in     = (const float*)d_in[2];  // [512]
    const float* Ws       = (const float*)d_in[3];  // [10, 512, 512]
    const float* bs       = (const float*)d_in[4];  // [10, 512]
    const float* W_out    = (const float*)d_in[5];  // [512, 1] -> 512 contiguous
    const float* b_out    = (const float*)d_in[6];  // [1]
    const int*   src      = (const int*)d_in[7];    // [160000]
    const int*   dst      = (const int*)d_in[8];    // [160000]
    float* out = (float*)d_out;                     // [10000]

    char* p = (char*)d_ws;
    auto alloc = [&](size_t bytes) {
        char* r = p;
        p += (bytes + 255) & ~size_t(255);
        return r;
    };
    int* deg     = (int*)alloc((size_t)N_NODES * 4);
    int* row_ptr = (int*)alloc((size_t)(N_NODES + 1) * 4);
    int* cursor  = (int*)alloc((size_t)N_NODES * 4);
    int* esrc    = (int*)alloc((size_t)N_EDGES * 4);
    float* agg6  = (float*)alloc((size_t)N_NODES * 6 * 4);
    float* v_a   = (float*)alloc(512 * 4);
    float* v_b   = (float*)alloc(512 * 4);
    float* gamma = (float*)alloc(DEPTH * 4);
    float* r_a   = (float*)alloc((size_t)N_NODES * 4);
    float* r_b   = (float*)alloc((size_t)N_NODES * 4);

    // ---- CSR build ----
    zero_int_kernel<<<(N_NODES + 255) / 256, 256, 0, stream>>>(deg, N_NODES);
    count_deg_kernel<<<(N_EDGES + 255) / 256, 256, 0, stream>>>(dst, deg, N_EDGES);
    scan_kernel<<<1, 1024, 0, stream>>>(deg, row_ptr, cursor);
    fill_edges_kernel<<<(N_EDGES + 255) / 256, 256, 0, stream>>>(src, dst, cursor, esrc, N_EDGES);

    // ---- backward weight chain: v = W_out; for l=9..0: gamma[l]=bs[l].v; v=Ws[l]@v ----
    hipMemcpyAsync(v_a, W_out, 512 * sizeof(float), hipMemcpyDeviceToDevice, stream);
    float* v_cur = v_a;
    float* v_nxt = v_b;
    for (int l = DEPTH - 1; l >= 0; l--) {
        matvec_gamma_kernel<<<128, 256, 0, stream>>>(Ws + (size_t)l * 512 * 512,
                                                     bs + (size_t)l * 512,
                                                     v_cur, v_nxt, gamma + l);
        float* t = v_cur; v_cur = v_nxt; v_nxt = t;
    }
    // v_cur == w~ = W1..W10 Wout

    // ---- input layer fused with projection: z = relu(agg6 W_in + b_in) . w~ ----
    aggregate6_kernel<<<(N_NODES * 8 + 255) / 256, 256, 0, stream>>>(features, row_ptr, esrc, agg6);
    input_z_kernel<<<N_NODES, 256, 0, stream>>>(agg6, W_in, b_in, v_cur, r_a);

    // ---- Horner: r <- A r + gamma[l];  final iter adds b_out and writes out ----
    float* r_cur = r_a;
    float* r_nxt = r_b;
    for (int l = 0; l < DEPTH; l++) {
        int last = (l == DEPTH - 1);
        col_agg_kernel<<<(N_NODES + 255) / 256, 256, 0, stream>>>(
            r_cur, row_ptr, esrc, gamma, l, b_out, last, last ? out : r_nxt);
        float* t = r_cur; r_cur = r_nxt; r_nxt = t;
    }
}